// Round 7
// baseline (412.390 us; speedup 1.0000x reference)
//
#include <hip/hip_runtime.h>
#include <hip/hip_bf16.h>

#define B_    8
#define N_    1024
#define C_    512
#define H_    4
#define HD_   128
#define BN_   (B_ * N_)      // 8192
#define QKVC_ 1536
#define SCALE_ 0.08838834764831845f  // 128^-0.5

typedef __bf16 bf16;
typedef __bf16 bf16x8 __attribute__((ext_vector_type(8)));
typedef float  floatx4 __attribute__((ext_vector_type(4)));

__device__ __forceinline__ void gload_lds16(const bf16* g, bf16* l) {
    __builtin_amdgcn_global_load_lds(
        (const __attribute__((address_space(1))) void*)g,
        (__attribute__((address_space(3))) void*)l, 16, 0, 0);
}

// ---------------------------------------------------------------------------
// Kernel 0: fp32 -> bf16 conversion for x, w_qkv, w_proj.
// ---------------------------------------------------------------------------
__global__ __launch_bounds__(256) void cvt_bf16(const float* __restrict__ x,  bf16* __restrict__ xb,
                                                const float* __restrict__ wq, bf16* __restrict__ wqb,
                                                const float* __restrict__ wp, bf16* __restrict__ wpb) {
    int id = blockIdx.x * 256 + threadIdx.x;
    const float* s; bf16* d; int off;
    if (id < 524288)      { s = x;  d = xb;  off = id; }
    else if (id < 622592) { s = wq; d = wqb; off = id - 524288; }
    else                  { s = wp; d = wpb; off = id - 622592; }
    const float4* sp = (const float4*)s + (size_t)off * 2;
    float4 f0 = sp[0], f1 = sp[1];
    bf16x8 v;
    v[0] = (bf16)f0.x; v[1] = (bf16)f0.y; v[2] = (bf16)f0.z; v[3] = (bf16)f0.w;
    v[4] = (bf16)f1.x; v[5] = (bf16)f1.y; v[6] = (bf16)f1.z; v[7] = (bf16)f1.w;
    ((bf16x8*)d)[off] = v;
}

// ---------------------------------------------------------------------------
// m97-class GEMM (proven): C[m][n] = sum_k A[m][k]*Bw[n][k] (+bias)
// XOR chunk swizzle, global_load_lds staging both operands.
// ---------------------------------------------------------------------------
template<int TN, int NOUT, bool F32OUT>
__global__ __launch_bounds__(256) void gemm_bt(const bf16* __restrict__ A,
                                               const bf16* __restrict__ Bw,
                                               const float* __restrict__ bias,
                                               void* __restrict__ Cout) {
    constexpr int NT = TN / 32;
    const int t = threadIdx.x;
    const int wave = t >> 6, lane = t & 63;
    const int quad = lane >> 4, l16 = lane & 15;
    const int ro = lane >> 3;
    const int ch = (lane & 7) ^ ro;

    const int m_base = blockIdx.x * 128;
    const int n_base = blockIdx.y * TN;
    const int wave_r = (wave & 1) * 64;
    const int wave_c = (wave >> 1) * (TN / 2);

    __shared__ bf16 As[128 * 64];
    __shared__ bf16 Bs[TN * 64];

    floatx4 acc[4][NT] = {};

    for (int k0 = 0; k0 < 512; k0 += 64) {
        __syncthreads();
#pragma unroll
        for (int j = 0; j < 4; j++) {
            int r0 = (wave * 4 + j) * 8;
            gload_lds16(A + (size_t)(m_base + r0 + ro) * 512 + k0 + ch * 8,
                        As + r0 * 64);
        }
#pragma unroll
        for (int j = 0; j < TN / 32; j++) {
            int r0 = (wave * (TN / 32) + j) * 8;
            gload_lds16(Bw + (size_t)(n_base + r0 + ro) * 512 + k0 + ch * 8,
                        Bs + r0 * 64);
        }
        __syncthreads();

#pragma unroll
        for (int kk = 0; kk < 2; kk++) {
            const int kc = kk * 4 + quad;
            bf16x8 af[4], bfr[NT];
#pragma unroll
            for (int mt = 0; mt < 4; mt++) {
                int r = wave_r + mt * 16 + l16;
                af[mt] = *(const bf16x8*)&As[r * 64 + ((kc ^ (r & 7)) * 8)];
            }
#pragma unroll
            for (int nt = 0; nt < NT; nt++) {
                int r = wave_c + nt * 16 + l16;
                bfr[nt] = *(const bf16x8*)&Bs[r * 64 + ((kc ^ (r & 7)) * 8)];
            }
#pragma unroll
            for (int mt = 0; mt < 4; mt++)
#pragma unroll
                for (int nt = 0; nt < NT; nt++)
                    acc[mt][nt] = __builtin_amdgcn_mfma_f32_16x16x32_bf16(
                        af[mt], bfr[nt], acc[mt][nt], 0, 0, 0);
        }
    }

#pragma unroll
    for (int nt = 0; nt < NT; nt++) {
        int col = n_base + wave_c + nt * 16 + l16;
        float bi = 0.f;
        if constexpr (F32OUT) bi = bias[col];
#pragma unroll
        for (int mt = 0; mt < 4; mt++) {
#pragma unroll
            for (int r = 0; r < 4; r++) {
                int row = m_base + wave_r + mt * 16 + quad * 4 + r;
                if constexpr (F32OUT)
                    ((float*)Cout)[(size_t)row * NOUT + col] = acc[mt][nt][r] + bi;
                else
                    ((bf16*)Cout)[(size_t)row * NOUT + col] = (bf16)acc[mt][nt][r];
            }
        }
    }
}

// ---------------------------------------------------------------------------
// Fused CIM flash attention, split-K (2 x 512 keys), DIRECT-K:
//   K B-fragments loaded straight global->VGPR (native B-operand layout,
//   16B/lane, 64B segments per key-row; all 4 waves share the tile via L1).
//   NO Kt LDS, NO K barriers — compiler pipelines kb loads across MFMAs
//   with fine-grained vmcnt.  V double-buffered in LDS, ONE barrier/iter.
//   LDS 25.6 KB; __launch_bounds__(256,3) -> 3+ blocks/CU.
// ---------------------------------------------------------------------------
__global__ __launch_bounds__(256, 3) void flash_attn(const bf16* __restrict__ qkv,
                                                     const float* __restrict__ w_main,
                                                     const float* __restrict__ w_rest,
                                                     bf16* __restrict__ po,
                                                     float* __restrict__ ml) {
    const int b = blockIdx.z >> 1, split = blockIdx.z & 1;
    const int head = blockIdx.y;
    const int n0 = blockIdx.x * 64;
    const int t = threadIdx.x;
    const int wave = t >> 6, lane = t & 63;
    const int quad = lane >> 4, l16 = lane & 15;

    float qs[H_];
#pragma unroll
    for (int j = 0; j < H_; j++) {
        float mij = (j == head) ? w_main[head]
                                : w_rest[head * (H_ - 1) + (j - (j > head ? 1 : 0))];
        qs[j] = mij * SCALE_;
    }

    __shared__ bf16 Vt[2][128][40];    // 2 x 10.2 KB
    __shared__ bf16 Pb[4][16][40];     // 5.1 KB  (total 25.6 KB)

    // Q' fragments (A-layout), mix+scale folded in
    bf16x8 qf[16];
    const int qrow = n0 + wave * 16 + l16;
    const bf16* qbase = qkv + (size_t)(b * N_ + qrow) * QKVC_;
#pragma unroll
    for (int kk = 0; kk < 16; kk++) {
        int kg = kk * 32 + quad * 8;
        bf16x8 v = *(const bf16x8*)(qbase + kg);
        float sc = qs[kg >> 7];
        bf16x8 q;
#pragma unroll
        for (int j = 0; j < 8; j++) q[j] = (bf16)((float)v[j] * sc);
        qf[kk] = q;
    }

    bf16x8 vones;
#pragma unroll
    for (int j = 0; j < 8; j++) vones[j] = (bf16)1.0f;

    floatx4 o[8] = {};
    float mrow[4] = {-1e30f, -1e30f, -1e30f, -1e30f};
    float lrow[4] = {0.f, 0.f, 0.f, 0.f};

    const bf16* kvbase = qkv + (size_t)(b * N_) * QKVC_;
    const int vg = t & 3, vp = t >> 2;
    const int m_begin = split * 512;

    // prologue: V tile 0 into Vt[0]
    {
        const bf16* vs = kvbase + (size_t)(m_begin + 8 * vg) * QKVC_ + 1024 + head * HD_ + 2 * vp;
        unsigned int dw[8];
#pragma unroll
        for (int j = 0; j < 8; j++)
            dw[j] = *(const unsigned int*)(vs + (size_t)j * QKVC_);
        uint4 lo, hi;
        lo.x = (dw[0] & 0xffffu) | (dw[1] << 16);
        lo.y = (dw[2] & 0xffffu) | (dw[3] << 16);
        lo.z = (dw[4] & 0xffffu) | (dw[5] << 16);
        lo.w = (dw[6] & 0xffffu) | (dw[7] << 16);
        hi.x = (dw[0] >> 16) | (dw[1] & 0xffff0000u);
        hi.y = (dw[2] >> 16) | (dw[3] & 0xffff0000u);
        hi.z = (dw[4] >> 16) | (dw[5] & 0xffff0000u);
        hi.w = (dw[6] >> 16) | (dw[7] & 0xffff0000u);
        *(uint4*)&Vt[0][2 * vp][8 * vg] = lo;
        *(uint4*)&Vt[0][2 * vp + 1][8 * vg] = hi;
    }
    __syncthreads();

#pragma unroll 1
    for (int it = 0; it < 16; ++it) {
        const int cur = it & 1, nxt = cur ^ 1;
        const int m0 = m_begin + it * 32;

        // issue V reg loads for tile it+1 (consumed at bottom of this iter)
        unsigned int dwn[8];
        if (it < 15) {
            const bf16* vs = kvbase + (size_t)(m0 + 32 + 8 * vg) * QKVC_ + 1024 + head * HD_ + 2 * vp;
#pragma unroll
            for (int j = 0; j < 8; j++)
                dwn[j] = *(const unsigned int*)(vs + (size_t)j * QKVC_);
        }

        // scores: S[16 x 32] = Q'[16 x 512] @ Kcat^T, kb direct from global
        floatx4 s[2] = {};
#pragma unroll
        for (int kk = 0; kk < 16; kk++) {
#pragma unroll
            for (int nt = 0; nt < 2; nt++) {
                bf16x8 kb = *(const bf16x8*)(kvbase +
                    (size_t)(m0 + nt * 16 + l16) * QKVC_ + 512 + kk * 32 + quad * 8);
                s[nt] = __builtin_amdgcn_mfma_f32_16x16x32_bf16(qf[kk], kb, s[nt], 0, 0, 0);
            }
        }

        // online softmax
#pragma unroll
        for (int r = 0; r < 4; r++) {
            float mx = fmaxf(s[0][r], s[1][r]);
#pragma unroll
            for (int off = 1; off < 16; off <<= 1) mx = fmaxf(mx, __shfl_xor(mx, off));
            float mnew = fmaxf(mrow[r], mx);
            float alpha = __expf(mrow[r] - mnew);
            mrow[r] = mnew;
            s[0][r] = __expf(s[0][r] - mnew);
            s[1][r] = __expf(s[1][r] - mnew);
            lrow[r] *= alpha;
#pragma unroll
            for (int nt = 0; nt < 8; nt++) o[nt][r] *= alpha;
        }

        // P: D-layout -> LDS -> A-layout (wave-private, no barrier)
#pragma unroll
        for (int nt = 0; nt < 2; nt++)
#pragma unroll
            for (int r = 0; r < 4; r++)
                Pb[wave][quad * 4 + r][nt * 16 + l16] = (bf16)s[nt][r];

        bf16x8 pf = *(const bf16x8*)&Pb[wave][l16][quad * 8];

        // row sums via ones-MFMA
        floatx4 s9 = __builtin_amdgcn_mfma_f32_16x16x32_bf16(
            pf, vones, (floatx4){0.f, 0.f, 0.f, 0.f}, 0, 0, 0);
#pragma unroll
        for (int r = 0; r < 4; r++) lrow[r] += s9[r];

        // O += P @ V from Vt[cur]
#pragma unroll
        for (int nt = 0; nt < 8; nt++) {
            bf16x8 vf = *(const bf16x8*)&Vt[cur][nt * 16 + l16][quad * 8];
            o[nt] = __builtin_amdgcn_mfma_f32_16x16x32_bf16(pf, vf, o[nt], 0, 0, 0);
        }

        // pack + publish V tile it+1 into Vt[nxt]
        if (it < 15) {
            uint4 lo, hi;
            lo.x = (dwn[0] & 0xffffu) | (dwn[1] << 16);
            lo.y = (dwn[2] & 0xffffu) | (dwn[3] << 16);
            lo.z = (dwn[4] & 0xffffu) | (dwn[5] << 16);
            lo.w = (dwn[6] & 0xffffu) | (dwn[7] << 16);
            hi.x = (dwn[0] >> 16) | (dwn[1] & 0xffff0000u);
            hi.y = (dwn[2] >> 16) | (dwn[3] & 0xffff0000u);
            hi.z = (dwn[4] >> 16) | (dwn[5] & 0xffff0000u);
            hi.w = (dwn[6] >> 16) | (dwn[7] & 0xffff0000u);
            *(uint4*)&Vt[nxt][2 * vp][8 * vg] = lo;
            *(uint4*)&Vt[nxt][2 * vp + 1][8 * vg] = hi;
        }
        __syncthreads();
    }

    // epilogue: unnormalized O + (m,l)
    bf16* pod = po + (size_t)split * BN_ * C_;
#pragma unroll
    for (int r = 0; r < 4; r++) {
        int row = n0 + wave * 16 + quad * 4 + r;
        bf16* dst = pod + (size_t)(b * N_ + row) * C_ + head * HD_;
#pragma unroll
        for (int nt = 0; nt < 8; nt++)
            dst[nt * 16 + l16] = (bf16)o[nt][r];
        if (l16 == 0) {
            size_t idx = ((size_t)split * BN_ + b * N_ + row) * H_ + head;
            ml[idx * 2]     = mrow[r];
            ml[idx * 2 + 1] = lrow[r];
        }
    }
}

// ---------------------------------------------------------------------------
// Merge the two splits: out = (e0*O0 + e1*O1) / (e0*l0 + e1*l1)
// ---------------------------------------------------------------------------
__global__ __launch_bounds__(256) void merge_splits(const bf16* __restrict__ po,
                                                    const float* __restrict__ ml,
                                                    bf16* __restrict__ attn) {
    int id = blockIdx.x * 256 + threadIdx.x;     // 524288 threads
    int rh = id >> 4;                            // (b*N+row)*H + head
    int d0 = (id & 15) * 8;
    int row = rh >> 2, h = rh & 3;

    float m0v = ml[(size_t)rh * 2],              l0 = ml[(size_t)rh * 2 + 1];
    float m1v = ml[(size_t)(BN_ * H_ + rh) * 2], l1 = ml[(size_t)(BN_ * H_ + rh) * 2 + 1];
    float ms = fmaxf(m0v, m1v);
    float e0 = __expf(m0v - ms), e1 = __expf(m1v - ms);
    float inv = 1.0f / (e0 * l0 + e1 * l1);
    float w0 = e0 * inv, w1 = e1 * inv;

    size_t off = (size_t)row * C_ + h * HD_ + d0;
    bf16x8 a = *(const bf16x8*)(po + off);
    bf16x8 bq = *(const bf16x8*)(po + (size_t)BN_ * C_ + off);
    bf16x8 ov;
#pragma unroll
    for (int j = 0; j < 8; j++)
        ov[j] = (bf16)((float)a[j] * w0 + (float)bq[j] * w1);
    *(bf16x8*)(attn + off) = ov;
}

// ---------------------------------------------------------------------------
extern "C" void kernel_launch(void* const* d_in, const int* in_sizes, int n_in,
                              void* d_out, int out_size, void* d_ws, size_t ws_size,
                              hipStream_t stream) {
    const float* x      = (const float*)d_in[0];
    const float* w_qkv  = (const float*)d_in[1];
    const float* w_proj = (const float*)d_in[2];
    const float* b_proj = (const float*)d_in[3];
    const float* w_main = (const float*)d_in[4];
    const float* w_rest = (const float*)d_in[5];
    float* out = (float*)d_out;

    bf16* qkv = (bf16*)d_ws;                           // [8192,1536]
    bf16* xb  = qkv + (size_t)BN_ * QKVC_;             // [8192,512]
    bf16* wqb = xb + (size_t)BN_ * C_;                 // [1536,512]
    bf16* wpb = wqb + 3 * C_ * C_;                     // [512,512]
    bf16* po  = wpb + C_ * C_;                         // 2 x [8192,512]
    float* ml = (float*)(po + (size_t)2 * BN_ * C_);   // 2 x [32768][2]
    bf16* attn = xb;  // xb dead after qkv_gemm

    cvt_bf16<<<2560, 256, 0, stream>>>(x, xb, w_qkv, wqb, w_proj, wpb);
    gemm_bt<128, QKVC_, false><<<dim3(64, 12), 256, 0, stream>>>(xb, wqb, nullptr, qkv);
    flash_attn<<<dim3(N_ / 64, H_, B_ * 2), 256, 0, stream>>>(qkv, w_main, w_rest, po, ml);
    merge_splits<<<2048, 256, 0, stream>>>(po, ml, attn);
    gemm_bt<64, C_, true><<<dim3(64, 8), 256, 0, stream>>>(attn, wpb, b_proj, out);
}

// Round 8
// 199.873 us; speedup vs baseline: 2.0633x; 2.0633x over previous
//
#include <hip/hip_runtime.h>
#include <hip/hip_bf16.h>

#define B_    8
#define N_    1024
#define C_    512
#define H_    4
#define HD_   128
#define BN_   (B_ * N_)      // 8192
#define QKVC_ 1536
#define SCALE_ 0.08838834764831845f  // 128^-0.5

typedef __bf16 bf16;
typedef __bf16 bf16x8 __attribute__((ext_vector_type(8)));
typedef float  floatx4 __attribute__((ext_vector_type(4)));

__device__ __forceinline__ void gload_lds16(const bf16* g, bf16* l) {
    __builtin_amdgcn_global_load_lds(
        (const __attribute__((address_space(1))) void*)g,
        (__attribute__((address_space(3))) void*)l, 16, 0, 0);
}

// ---------------------------------------------------------------------------
// Kernel 0: fp32 -> bf16 conversion for x, w_qkv, w_proj.
// ---------------------------------------------------------------------------
__global__ __launch_bounds__(256) void cvt_bf16(const float* __restrict__ x,  bf16* __restrict__ xb,
                                                const float* __restrict__ wq, bf16* __restrict__ wqb,
                                                const float* __restrict__ wp, bf16* __restrict__ wpb) {
    int id = blockIdx.x * 256 + threadIdx.x;
    const float* s; bf16* d; int off;
    if (id < 524288)      { s = x;  d = xb;  off = id; }
    else if (id < 622592) { s = wq; d = wqb; off = id - 524288; }
    else                  { s = wp; d = wpb; off = id - 622592; }
    const float4* sp = (const float4*)s + (size_t)off * 2;
    float4 f0 = sp[0], f1 = sp[1];
    bf16x8 v;
    v[0] = (bf16)f0.x; v[1] = (bf16)f0.y; v[2] = (bf16)f0.z; v[3] = (bf16)f0.w;
    v[4] = (bf16)f1.x; v[5] = (bf16)f1.y; v[6] = (bf16)f1.z; v[7] = (bf16)f1.w;
    ((bf16x8*)d)[off] = v;
}

// ---------------------------------------------------------------------------
// m97-class GEMM (proven): C[m][n] = sum_k A[m][k]*Bw[n][k] (+bias)
// ---------------------------------------------------------------------------
template<int TN, int NOUT, bool F32OUT>
__global__ __launch_bounds__(256) void gemm_bt(const bf16* __restrict__ A,
                                               const bf16* __restrict__ Bw,
                                               const float* __restrict__ bias,
                                               void* __restrict__ Cout) {
    constexpr int NT = TN / 32;
    const int t = threadIdx.x;
    const int wave = t >> 6, lane = t & 63;
    const int quad = lane >> 4, l16 = lane & 15;
    const int ro = lane >> 3;
    const int ch = (lane & 7) ^ ro;

    const int m_base = blockIdx.x * 128;
    const int n_base = blockIdx.y * TN;
    const int wave_r = (wave & 1) * 64;
    const int wave_c = (wave >> 1) * (TN / 2);

    __shared__ bf16 As[128 * 64];
    __shared__ bf16 Bs[TN * 64];

    floatx4 acc[4][NT] = {};

    for (int k0 = 0; k0 < 512; k0 += 64) {
        __syncthreads();
#pragma unroll
        for (int j = 0; j < 4; j++) {
            int r0 = (wave * 4 + j) * 8;
            gload_lds16(A + (size_t)(m_base + r0 + ro) * 512 + k0 + ch * 8,
                        As + r0 * 64);
        }
#pragma unroll
        for (int j = 0; j < TN / 32; j++) {
            int r0 = (wave * (TN / 32) + j) * 8;
            gload_lds16(Bw + (size_t)(n_base + r0 + ro) * 512 + k0 + ch * 8,
                        Bs + r0 * 64);
        }
        __syncthreads();

#pragma unroll
        for (int kk = 0; kk < 2; kk++) {
            const int kc = kk * 4 + quad;
            bf16x8 af[4], bfr[NT];
#pragma unroll
            for (int mt = 0; mt < 4; mt++) {
                int r = wave_r + mt * 16 + l16;
                af[mt] = *(const bf16x8*)&As[r * 64 + ((kc ^ (r & 7)) * 8)];
            }
#pragma unroll
            for (int nt = 0; nt < NT; nt++) {
                int r = wave_c + nt * 16 + l16;
                bfr[nt] = *(const bf16x8*)&Bs[r * 64 + ((kc ^ (r & 7)) * 8)];
            }
#pragma unroll
            for (int mt = 0; mt < 4; mt++)
#pragma unroll
                for (int nt = 0; nt < NT; nt++)
                    acc[mt][nt] = __builtin_amdgcn_mfma_f32_16x16x32_bf16(
                        af[mt], bfr[nt], acc[mt][nt], 0, 0, 0);
        }
    }

#pragma unroll
    for (int nt = 0; nt < NT; nt++) {
        int col = n_base + wave_c + nt * 16 + l16;
        float bi = 0.f;
        if constexpr (F32OUT) bi = bias[col];
#pragma unroll
        for (int mt = 0; mt < 4; mt++) {
#pragma unroll
            for (int r = 0; r < 4; r++) {
                int row = m_base + wave_r + mt * 16 + quad * 4 + r;
                if constexpr (F32OUT)
                    ((float*)Cout)[(size_t)row * NOUT + col] = acc[mt][nt][r] + bi;
                else
                    ((bf16*)Cout)[(size_t)row * NOUT + col] = (bf16)acc[mt][nt][r];
            }
        }
    }
}

// ---------------------------------------------------------------------------
// Fused CIM flash attention — SHARED-SCORE version.
// One score pass (32 MFMA over the concatenated 512-wide k-row) yields
// S_j = q_j.k_j for ALL 4 input heads (accumulate kk/4 separately).
// A 64-FMA register mix then produces TWO output heads' logits per block:
//   S'_i = sum_j M[i,j]*SCALE*S_j,  i in {2*hg, 2*hg+1}.
// Split-K over keys (2 x 512).  Grid (16, 2, 16) = 512 blocks.
// Unnormalized O (bf16) + (m,l) fp32 out; merged later.
// ---------------------------------------------------------------------------
__global__ __launch_bounds__(256, 2) void flash_attn(const bf16* __restrict__ qkv,
                                                     const float* __restrict__ w_main,
                                                     const float* __restrict__ w_rest,
                                                     bf16* __restrict__ po,
                                                     float* __restrict__ ml) {
    const int b = blockIdx.z >> 1, split = blockIdx.z & 1;
    const int hg = blockIdx.y;              // heads 2hg, 2hg+1
    const int n0 = blockIdx.x * 64;
    const int t = threadIdx.x;
    const int wave = t >> 6, lane = t & 63;
    const int quad = lane >> 4, l16 = lane & 15;

    // mix coefficients c[p][j] = M[2hg+p][j] * SCALE
    float c[2][4];
#pragma unroll
    for (int p = 0; p < 2; p++) {
        int i = 2 * hg + p;
#pragma unroll
        for (int j = 0; j < 4; j++) {
            float mij = (j == i) ? w_main[i]
                                 : w_rest[i * (H_ - 1) + (j - (j > i ? 1 : 0))];
            c[p][j] = mij * SCALE_;
        }
    }

    __shared__ bf16 Kt[32 * 512];        // 32 KB, XOR-swizzled (all 4 heads' k)
    __shared__ bf16 Vt[256][40];         // 20 KB: head-pair's 256 V-dims x 32 keys
    __shared__ bf16 Pb[4][2][16][40];    // 10.2 KB  (total 62 KB -> 2 blk/CU)

    // raw Q fragments (A-layout) — NO scale (mix applied to fp32 scores)
    bf16x8 qf[16];
    const int qrow = n0 + wave * 16 + l16;
    const bf16* qbase = qkv + (size_t)(b * N_ + qrow) * QKVC_;
#pragma unroll
    for (int kk = 0; kk < 16; kk++)
        qf[kk] = *(const bf16x8*)(qbase + kk * 32 + quad * 8);

    bf16x8 vones;
#pragma unroll
    for (int j = 0; j < 8; j++) vones[j] = (bf16)1.0f;

    floatx4 o[2][8] = {};
    float mrow[2][4], lrow[2][4];
#pragma unroll
    for (int p = 0; p < 2; p++)
#pragma unroll
        for (int r = 0; r < 4; r++) { mrow[p][r] = -1e30f; lrow[p][r] = 0.f; }

    const bf16* kvbase = qkv + (size_t)(b * N_) * QKVC_;
    const int vg = t & 3, vp = t >> 2;   // V-stage: keys 8vg..+7, dims 4vp..+3
    const int m_begin = split * 512;

    for (int m0 = m_begin; m0 < m_begin + 512; m0 += 32) {
        __syncthreads();
        // K tile via DMA: wave w stages rows 8w..8w+7 (XOR chunk swizzle)
#pragma unroll
        for (int j = 0; j < 8; j++) {
            int r = wave * 8 + j;
            gload_lds16(kvbase + (size_t)(m0 + r) * QKVC_ + 512 + ((lane ^ (r & 7)) << 3),
                        Kt + r * 512);
        }
        // V tile (head-pair, 256 dims): register transpose, 8B loads
        {
            const bf16* vs = kvbase + (size_t)(m0 + 8 * vg) * QKVC_ + 1024 + hg * 256 + 4 * vp;
            uint2 dv[8];
#pragma unroll
            for (int j = 0; j < 8; j++)
                dv[j] = *(const uint2*)(vs + (size_t)j * QKVC_);
            uint4 r0, r1, r2, r3;
            r0.x = (dv[0].x & 0xffffu) | (dv[1].x << 16);
            r0.y = (dv[2].x & 0xffffu) | (dv[3].x << 16);
            r0.z = (dv[4].x & 0xffffu) | (dv[5].x << 16);
            r0.w = (dv[6].x & 0xffffu) | (dv[7].x << 16);
            r1.x = (dv[0].x >> 16) | (dv[1].x & 0xffff0000u);
            r1.y = (dv[2].x >> 16) | (dv[3].x & 0xffff0000u);
            r1.z = (dv[4].x >> 16) | (dv[5].x & 0xffff0000u);
            r1.w = (dv[6].x >> 16) | (dv[7].x & 0xffff0000u);
            r2.x = (dv[0].y & 0xffffu) | (dv[1].y << 16);
            r2.y = (dv[2].y & 0xffffu) | (dv[3].y << 16);
            r2.z = (dv[4].y & 0xffffu) | (dv[5].y << 16);
            r2.w = (dv[6].y & 0xffffu) | (dv[7].y << 16);
            r3.x = (dv[0].y >> 16) | (dv[1].y & 0xffff0000u);
            r3.y = (dv[2].y >> 16) | (dv[3].y & 0xffff0000u);
            r3.z = (dv[4].y >> 16) | (dv[5].y & 0xffff0000u);
            r3.w = (dv[6].y >> 16) | (dv[7].y & 0xffff0000u);
            *(uint4*)&Vt[4 * vp + 0][8 * vg] = r0;
            *(uint4*)&Vt[4 * vp + 1][8 * vg] = r1;
            *(uint4*)&Vt[4 * vp + 2][8 * vg] = r2;
            *(uint4*)&Vt[4 * vp + 3][8 * vg] = r3;
        }
        __syncthreads();

        // Per-head scores: s[j] = q_j @ k_j^T  (one pass over 512 cols)
        floatx4 s[4][2] = {};
#pragma unroll
        for (int kk = 0; kk < 16; kk++) {
#pragma unroll
            for (int nt = 0; nt < 2; nt++) {
                int r = nt * 16 + l16;
                bf16x8 kb = *(const bf16x8*)&Kt[r * 512 + (((kk * 4 + quad) ^ (r & 7)) << 3)];
                s[kk >> 2][nt] = __builtin_amdgcn_mfma_f32_16x16x32_bf16(
                    qf[kk], kb, s[kk >> 2][nt], 0, 0, 0);
            }
        }

        // Per output head p: mix -> online softmax -> P staging -> PV
#pragma unroll
        for (int p = 0; p < 2; p++) {
            floatx4 ms0, ms1;
#pragma unroll
            for (int r = 0; r < 4; r++) {
                ms0[r] = c[p][0] * s[0][0][r] + c[p][1] * s[1][0][r]
                       + c[p][2] * s[2][0][r] + c[p][3] * s[3][0][r];
                ms1[r] = c[p][0] * s[0][1][r] + c[p][1] * s[1][1][r]
                       + c[p][2] * s[2][1][r] + c[p][3] * s[3][1][r];
            }
#pragma unroll
            for (int r = 0; r < 4; r++) {
                float mx = fmaxf(ms0[r], ms1[r]);
#pragma unroll
                for (int off = 1; off < 16; off <<= 1) mx = fmaxf(mx, __shfl_xor(mx, off));
                float mnew = fmaxf(mrow[p][r], mx);
                float alpha = __expf(mrow[p][r] - mnew);
                mrow[p][r] = mnew;
                ms0[r] = __expf(ms0[r] - mnew);
                ms1[r] = __expf(ms1[r] - mnew);
                lrow[p][r] *= alpha;
#pragma unroll
                for (int nt = 0; nt < 8; nt++) o[p][nt][r] *= alpha;
            }

            // P: D-layout -> LDS -> A-layout (wave-private, no barrier)
#pragma unroll
            for (int r = 0; r < 4; r++) {
                Pb[wave][p][quad * 4 + r][l16]      = (bf16)ms0[r];
                Pb[wave][p][quad * 4 + r][16 + l16] = (bf16)ms1[r];
            }
            bf16x8 pf = *(const bf16x8*)&Pb[wave][p][l16][quad * 8];

            // row sums via ones-MFMA
            floatx4 s9 = __builtin_amdgcn_mfma_f32_16x16x32_bf16(
                pf, vones, (floatx4){0.f, 0.f, 0.f, 0.f}, 0, 0, 0);
#pragma unroll
            for (int r = 0; r < 4; r++) lrow[p][r] += s9[r];

            // O_p += P_p @ V_p  (V rows p*128 .. p*128+127 of Vt)
#pragma unroll
            for (int nt = 0; nt < 8; nt++) {
                bf16x8 vf = *(const bf16x8*)&Vt[p * 128 + nt * 16 + l16][quad * 8];
                o[p][nt] = __builtin_amdgcn_mfma_f32_16x16x32_bf16(pf, vf, o[p][nt], 0, 0, 0);
            }
        }
    }

    // epilogue: unnormalized O + (m,l) for both heads
    bf16* pod = po + (size_t)split * BN_ * C_;
#pragma unroll
    for (int p = 0; p < 2; p++) {
        int head = 2 * hg + p;
#pragma unroll
        for (int r = 0; r < 4; r++) {
            int row = n0 + wave * 16 + quad * 4 + r;
            bf16* dst = pod + (size_t)(b * N_ + row) * C_ + head * HD_;
#pragma unroll
            for (int nt = 0; nt < 8; nt++)
                dst[nt * 16 + l16] = (bf16)o[p][nt][r];
            if (l16 == 0) {
                size_t idx = ((size_t)split * BN_ + b * N_ + row) * H_ + head;
                ml[idx * 2]     = mrow[p][r];
                ml[idx * 2 + 1] = lrow[p][r];
            }
        }
    }
}

// ---------------------------------------------------------------------------
// Merge the two splits: out = (e0*O0 + e1*O1) / (e0*l0 + e1*l1)
// ---------------------------------------------------------------------------
__global__ __launch_bounds__(256) void merge_splits(const bf16* __restrict__ po,
                                                    const float* __restrict__ ml,
                                                    bf16* __restrict__ attn) {
    int id = blockIdx.x * 256 + threadIdx.x;     // 524288 threads
    int rh = id >> 4;                            // (b*N+row)*H + head
    int d0 = (id & 15) * 8;
    int row = rh >> 2, h = rh & 3;

    float m0v = ml[(size_t)rh * 2],              l0 = ml[(size_t)rh * 2 + 1];
    float m1v = ml[(size_t)(BN_ * H_ + rh) * 2], l1 = ml[(size_t)(BN_ * H_ + rh) * 2 + 1];
    float ms = fmaxf(m0v, m1v);
    float e0 = __expf(m0v - ms), e1 = __expf(m1v - ms);
    float inv = 1.0f / (e0 * l0 + e1 * l1);
    float w0 = e0 * inv, w1 = e1 * inv;

    size_t off = (size_t)row * C_ + h * HD_ + d0;
    bf16x8 a = *(const bf16x8*)(po + off);
    bf16x8 bq = *(const bf16x8*)(po + (size_t)BN_ * C_ + off);
    bf16x8 ov;
#pragma unroll
    for (int j = 0; j < 8; j++)
        ov[j] = (bf16)((float)a[j] * w0 + (float)bq[j] * w1);
    *(bf16x8*)(attn + off) = ov;
}

// ---------------------------------------------------------------------------
extern "C" void kernel_launch(void* const* d_in, const int* in_sizes, int n_in,
                              void* d_out, int out_size, void* d_ws, size_t ws_size,
                              hipStream_t stream) {
    const float* x      = (const float*)d_in[0];
    const float* w_qkv  = (const float*)d_in[1];
    const float* w_proj = (const float*)d_in[2];
    const float* b_proj = (const float*)d_in[3];
    const float* w_main = (const float*)d_in[4];
    const float* w_rest = (const float*)d_in[5];
    float* out = (float*)d_out;

    bf16* qkv = (bf16*)d_ws;                           // [8192,1536]
    bf16* xb  = qkv + (size_t)BN_ * QKVC_;             // [8192,512]
    bf16* wqb = xb + (size_t)BN_ * C_;                 // [1536,512]
    bf16* wpb = wqb + 3 * C_ * C_;                     // [512,512]
    bf16* po  = wpb + C_ * C_;                         // 2 x [8192,512]
    float* ml = (float*)(po + (size_t)2 * BN_ * C_);   // 2 x [32768][2]
    bf16* attn = xb;  // xb dead after qkv_gemm

    cvt_bf16<<<2560, 256, 0, stream>>>(x, xb, w_qkv, wqb, w_proj, wpb);
    gemm_bt<128, QKVC_, false><<<dim3(64, 12), 256, 0, stream>>>(xb, wqb, nullptr, qkv);
    flash_attn<<<dim3(N_ / 64, 2, B_ * 2), 256, 0, stream>>>(qkv, w_main, w_rest, po, ml);
    merge_splits<<<2048, 256, 0, stream>>>(po, ml, attn);
    gemm_bt<64, C_, true><<<dim3(64, 8), 256, 0, stream>>>(attn, wpb, b_proj, out);
}